// Round 6
// baseline (258.581 us; speedup 1.0000x reference)
//
#include <hip/hip_runtime.h>
#include <stdint.h>

#define NPIX 16384
#define IMW 128
#define NIMG 8
#define NLVL 11
#define BIGK 0xFFFFFFFFu
#define IMASK 16383u

// ---------------- prep: sigmoid/normalize/quantize, once per image ----------------
// Also publishes the global argmin key (root of the full-grid component) so the
// l >= maxL ccl blocks need no image data at all.
__global__ __launch_bounds__(1024) void prep_kernel(const float* __restrict__ model_output,
                                                    const float* __restrict__ labels,
                                                    uint8_t* __restrict__ lvl_all,
                                                    int* __restrict__ maxL_all,
                                                    unsigned* __restrict__ argmin_all)
{
    int img = blockIdx.x;
    int tid = threadIdx.x;
    unsigned lane = tid & 63u;
    bool ismask = img < 4;
    const float* src = ismask ? (labels + (size_t)img * NPIX)
                              : (model_output + (size_t)(img - 4) * NPIX);
    uint8_t* lvl = lvl_all + (size_t)img * NPIX;

    __shared__ float s_f[32];
    __shared__ unsigned s_u[32];
    __shared__ float s_mnmx[2];

    float mn = 0.f, mx = 1.f;
    if (!ismask) {
        float lmn = 1e30f, lmx = -1e30f;
        for (int i = tid; i < NPIX; i += 1024) {
            float s = 1.0f / (1.0f + expf(-src[i]));
            lmn = fminf(lmn, s); lmx = fmaxf(lmx, s);
        }
        for (int off = 32; off > 0; off >>= 1) {
            lmn = fminf(lmn, __shfl_down(lmn, off));
            lmx = fmaxf(lmx, __shfl_down(lmx, off));
        }
        int wv = tid >> 6;
        if (lane == 0) { s_f[wv] = lmn; s_f[16 + wv] = lmx; }
        __syncthreads();
        if (tid == 0) {
            float a = s_f[0], c = s_f[16];
            for (int w = 1; w < 16; ++w) { a = fminf(a, s_f[w]); c = fmaxf(c, s_f[16 + w]); }
            s_mnmx[0] = a; s_mnmx[1] = c;
        }
        __syncthreads();
        mn = s_mnmx[0]; mx = s_mnmx[1];
    }
    float denom = mx - mn;
    if (denom <= 0.f) denom = 1.f;

    unsigned lmaxk = 0;
    unsigned bestk = BIGK;
    for (int i = tid; i < NPIX; i += 1024) {
        int L;
        if (ismask) L = (int)rintf(src[i] * 10.0f);
        else {
            float s = 1.0f / (1.0f + expf(-src[i]));
            L = (int)rintf((s - mn) / denom * 10.0f);
        }
        lvl[i] = (uint8_t)L;
        unsigned key = ((unsigned)L << 14) | (unsigned)i;
        lmaxk = max(lmaxk, (unsigned)L);
        bestk = min(bestk, key);
    }
    for (int off = 32; off > 0; off >>= 1) {
        lmaxk = max(lmaxk, (unsigned)__shfl_down((int)lmaxk, off));
        bestk = min(bestk, (unsigned)__shfl_down((int)bestk, off));
    }
    if (lane == 0) { s_u[tid >> 6] = lmaxk; s_u[16 + (tid >> 6)] = bestk; }
    __syncthreads();
    if (tid == 0) {
        unsigned m = s_u[0], b = s_u[16];
        for (int w = 1; w < 16; ++w) { m = max(m, s_u[w]); b = min(b, s_u[16 + w]); }
        maxL_all[img] = (int)m;
        argmin_all[img] = b & IMASK;
    }
}

// ---------------- one block per (image, threshold): min-key CCL ----------------
// f[i] (u32 key (lvl<<14)|idx) init = horizontal-run min key (ballot+segmented
// prefix-min; BIGK if inactive). Then FastSV-style rounds over dedup'd vertical
// + segment-boundary edges: grandparent reads + atomicMin hooking/shortcutting
// -> distance-to-min doubles per round, O(log) rounds, no CAS, no find chains.
// Emits bitmap: bit i == 1 iff i is the min-key root of its component in S_l.
__global__ __launch_bounds__(1024) void ccl_kernel(const uint8_t* __restrict__ lvl_all,
                                                   const int* __restrict__ maxL_all,
                                                   const unsigned* __restrict__ argmin_all,
                                                   unsigned long long* __restrict__ bits_all)
{
    __shared__ unsigned s_f[NPIX];   // 64 KB — the only LDS array

    int img = blockIdx.x / NLVL;
    int l   = blockIdx.x % NLVL;
    int tid = threadIdx.x;
    unsigned lane = tid & 63u;
    const uint8_t* lv = lvl_all + (size_t)img * NPIX;
    unsigned long long* bits = bits_all + ((size_t)img * NLVL + l) * 256;
    int maxL = maxL_all[img];

    if (l >= maxL) {   // whole grid one component: root = precomputed argmin
        unsigned win = argmin_all[img];
        for (int w = tid; w < 256; w += 1024)
            bits[w] = ((win >> 6) == (unsigned)w) ? (1ull << (win & 63u)) : 0ull;
        return;
    }

    unsigned myKey[16];   // own run-leader key (static pointer into s_f)
    unsigned upKey[16];   // up-neighbor's run-leader key (static pointer)

    // ---- Phase A: horizontal runs -> f = run min-key (ballot + segmented scan).
    // Wave lanes cover 64 consecutive pixels; rows = 128 px = 2 segments, so
    // segments never straddle rows.
#pragma unroll
    for (int k = 0; k < 16; ++k) {
        int i = tid + k * 1024;
        uint8_t Lv = lv[i];
        bool act = (int)Lv <= l;
        unsigned long long m = __ballot(act);
        unsigned key = act ? (((unsigned)Lv << 14) | (unsigned)i) : BIGK;
        unsigned long long lowmask = (1ull << lane) - 1ull;
        unsigned long long zb = (~m) & lowmask;
        int runstart = zb ? (64 - __clzll(zb)) : 0;
        unsigned v = key;
#pragma unroll
        for (int d = 1; d < 64; d <<= 1) {
            unsigned o = __shfl_up(v, d, 64);
            if ((int)lane - d >= runstart) v = min(v, o);
        }
        unsigned long long za = (lane == 63u) ? 0ull : ((~m) >> (lane + 1));
        int runend = za ? ((int)lane + __ffsll((long long)za) - 1) : 63;
        unsigned rmin = __shfl(v, runend, 64);
        unsigned fi = act ? rmin : BIGK;
        s_f[i] = fi;
        myKey[k] = fi;
    }
    __syncthreads();

    // ---- edge masks (registers): dedup'd vertical + segment-boundary edges ----
    unsigned maskV = 0, maskB = 0;
#pragma unroll
    for (int k = 0; k < 16; ++k) {
        int i = tid + k * 1024;
        bool act = myKey[k] != BIGK;
        unsigned uk = BIGK;
        if (i >= IMW) uk = s_f[i - IMW];
        upKey[k] = uk;
        bool upAct = uk != BIGK;
        int leftAct   = __shfl_up(act ? 1 : 0, 1, 64);
        int upleftAct = __shfl_up(upAct ? 1 : 0, 1, 64);
        bool v = act && upAct;
        // keep only the leftmost pixel of each run-pair overlap (lane 0 can't
        // see its left neighbor -> keep unconditionally; duplicate is harmless)
        if (v && lane > 0u && leftAct && upleftAct) v = false;
        if (v) maskV |= 1u << k;
        if (lane == 0u && (i & (IMW - 1)) != 0 && act && s_f[i - 1] != BIGK)
            maskB |= 1u << k;
    }
    __syncthreads();

    // ---- FastSV rounds: grandparent hooking + shortcutting via atomicMin ----
    for (int it = 0; it < 40; ++it) {
        int changed = 0;
#pragma unroll
        for (int k = 0; k < 16; ++k) {
            if (maskV & (1u << k)) {
                unsigned pa = myKey[k] & IMASK;
                unsigned a  = s_f[pa];
                unsigned a2 = s_f[a & IMASK];
                unsigned pb = upKey[k] & IMASK;
                unsigned b  = s_f[pb];
                unsigned b2 = s_f[b & IMASK];
                unsigned mn = min(a2, b2);
                if (mn < a) { atomicMin(&s_f[pa], mn); changed = 1; }
                if (mn < b) { atomicMin(&s_f[pb], mn); changed = 1; }
            }
            if (maskB & (1u << k)) {
                int i = tid + k * 1024;
                unsigned pa = myKey[k] & IMASK;
                unsigned a  = s_f[pa];
                unsigned a2 = s_f[a & IMASK];
                unsigned pb = s_f[i - 1] & IMASK;   // any slot of left component works
                unsigned b  = s_f[pb];
                unsigned b2 = s_f[b & IMASK];
                unsigned mn = min(a2, b2);
                if (mn < a) { atomicMin(&s_f[pa], mn); changed = 1; }
                if (mn < b) { atomicMin(&s_f[pb], mn); changed = 1; }
            }
        }
        if (!__syncthreads_or(changed)) break;
    }

    // ---- emit root bitmap: root iff f[i] still equals own key ----
#pragma unroll
    for (int k = 0; k < 16; ++k) {
        int i = tid + k * 1024;
        unsigned cur = s_f[i];
        bool isroot = (cur != BIGK) && ((cur & IMASK) == (unsigned)i);
        unsigned long long m = __ballot(isroot);
        if (lane == 0u) bits[i >> 6] = m;
    }
}

// ---------------- deaths + top-256 selection per image ----------------
__global__ __launch_bounds__(1024) void death_kernel(const uint8_t* __restrict__ lvl_all,
                                                     const int* __restrict__ maxL_all,
                                                     const unsigned long long* __restrict__ bits_all,
                                                     float* __restrict__ outP,
                                                     float* __restrict__ outB,
                                                     float* __restrict__ outD)
{
    __shared__ unsigned long long s_bits[NLVL][256];   // 22528 B
    __shared__ uint8_t  s_lvl[NPIX];                   // 16384 B
    __shared__ uint8_t  s_rank[NPIX];                  // 16384 B (0xFF = not a candidate)
    __shared__ unsigned long long s_bm[256];           // bucket-r* index bitmap
    __shared__ unsigned s_keys[256];
    __shared__ unsigned s_pc[256];
    __shared__ unsigned s_hist[64];
    __shared__ uint8_t  s_rtab[NLVL][NLVL];
    __shared__ unsigned s_ctl[4];                      // r*, cnt_less, m, cnt

    int img = blockIdx.x;
    int tid = threadIdx.x;
    const uint8_t* lv = lvl_all + (size_t)img * NPIX;
    const unsigned long long* gbits = bits_all + (size_t)img * NLVL * 256;
    int maxL = maxL_all[img];

    for (int w = tid; w < NLVL * 256; w += 1024) ((unsigned long long*)s_bits)[w] = gbits[w];
    if (tid < 1024) ((uint4*)s_lvl)[tid] = ((const uint4*)lv)[tid];
    if (tid < 64) s_hist[tid] = 0;
    if (tid < 256) { s_bm[tid] = 0ull; s_keys[tid] = 0xFFFFFFFFu; }
    // rank table: rank(d,b) = #(of the 55 (dd,bb) pairs) with strictly larger f32
    // pers; order-isomorphic to float ordering; equal floats share rank -> tie by idx.
    if (tid < NLVL * NLVL) {
        int d = tid / NLVL, b = tid % NLVL;
        if (d > b) {
            float pers = (float)d / 10.0f - (float)b / 10.0f;
            unsigned rk = 0;
            for (int dd = 1; dd <= 10; ++dd)
                for (int bb = 0; bb < dd; ++bb) {
                    float pp = (float)dd / 10.0f - (float)bb / 10.0f;
                    rk += (pp > pers) ? 1u : 0u;
                }
            s_rtab[d][b] = (uint8_t)rk;
        }
    }
    __syncthreads();

    // ---- pass 1: candidates, ranks, histogram ----
    for (int i = tid; i < NPIX; i += 1024) {
        uint8_t r = 0xFF;
        int b = s_lvl[i];
        if ((s_bits[b][i >> 6] >> (i & 63)) & 1ull) {     // min-key root at birth
            int d = maxL;
            for (int l = b + 1; l <= maxL; ++l)
                if (!((s_bits[l][i >> 6] >> (i & 63)) & 1ull)) { d = l; break; }
            if (d > b) { r = s_rtab[d][b]; atomicAdd(&s_hist[r], 1u); }
        }
        s_rank[i] = r;
    }
    __syncthreads();

    // ---- cutoff: r* = first rank where cumulative count reaches 256 ----
    if (tid == 0) {
        unsigned cum = 0, rstar = 63, cless = 0;
        for (int r = 0; r < 56; ++r) {
            if (cum + s_hist[r] >= 256u && rstar == 63u) { rstar = r; cless = cum; }
            cum += s_hist[r];
        }
        if (rstar == 63u) cless = cum;                    // P < 256: take everything
        s_ctl[0] = rstar; s_ctl[1] = cless;
        s_ctl[2] = (rstar == 63u) ? 0u : (256u - cless);  // m slots from bucket r*
        s_ctl[3] = 0;
    }
    __syncthreads();
    unsigned rstar = s_ctl[0], cless = s_ctl[1], mneed = s_ctl[2];

    // ---- pass 2: compact rank<r* ; bitmap for rank==r* ----
    for (int i = tid; i < NPIX; i += 1024) {
        unsigned r = s_rank[i];
        if (r == 0xFFu) continue;
        if (r < rstar) {
            unsigned pos = atomicAdd(&s_ctl[3], 1u);
            if (pos < 256u) s_keys[pos] = (r << 14) | (unsigned)i;
        } else if (r == rstar) {
            atomicOr(&s_bm[i >> 6], 1ull << (i & 63));
        }
    }
    __syncthreads();

    // ---- bitonic sort 256 keys ascending == (rank asc, idx asc) ----
    for (unsigned k = 2; k <= 256; k <<= 1) {
        for (unsigned j = k >> 1; j > 0; j >>= 1) {
            if (tid < 256) {
                unsigned i = (unsigned)tid, ixj = i ^ j;
                if (ixj > i) {
                    unsigned x = s_keys[i], y = s_keys[ixj];
                    bool up = ((i & k) == 0);
                    if ((x > y) == up) { s_keys[i] = y; s_keys[ixj] = x; }
                }
            }
            __syncthreads();
        }
    }

    // ---- bucket r*: popcount-prefix -> each member computes its slot ----
    if (tid < 256) s_pc[tid] = (unsigned)__popcll(s_bm[tid]);
    __syncthreads();
    for (int d = 1; d < 256; d <<= 1) {                   // inclusive scan
        unsigned x = 0;
        if (tid < 256 && tid >= d) x = s_pc[tid - d];
        __syncthreads();
        if (tid < 256 && tid >= d) s_pc[tid] += x;
        __syncthreads();
    }
    for (int i = tid; i < NPIX; i += 1024) {
        if (s_rank[i] != rstar || rstar == 63u) continue;
        if (!((s_bm[i >> 6] >> (i & 63)) & 1ull)) continue;
        unsigned w = i >> 6;
        unsigned order = (w ? s_pc[w - 1] : 0u)
                       + (unsigned)__popcll(s_bm[w] & ((1ull << (i & 63)) - 1ull));
        if (order < mneed) s_keys[cless + order] = (rstar << 14) | (unsigned)i;
    }
    __syncthreads();

    // ---- emit ----
    for (int s = tid; s < 256; s += 1024) {
        unsigned key = s_keys[s];
        float p = 0.f, bv = 0.f, dv = 0.f;
        if (key != 0xFFFFFFFFu) {
            unsigned i = key & IMASK;
            int b = s_lvl[i];
            int d = maxL;
            for (int l = b + 1; l <= maxL; ++l)
                if (!((s_bits[l][i >> 6] >> (i & 63)) & 1ull)) { d = l; break; }
            bv = (float)b / 10.0f;
            dv = (float)d / 10.0f;
            p = dv - bv;
        }
        outP[img * 256 + s] = p;
        outB[img * 256 + s] = bv;
        outD[img * 256 + s] = dv;
    }
}

// ---------------- wasserstein matching + final loss ----------------
__global__ __launch_bounds__(1024) void wdist_kernel(const float* __restrict__ outP,
                                                     const float* __restrict__ outB,
                                                     const float* __restrict__ outD,
                                                     float* __restrict__ out)
{
    int tid = threadIdx.x;
    int s = tid >> 8;
    int slot = tid & 255;
    int mi = s * 256 + slot;
    int pi = (4 + s) * 256 + slot;
    float p1 = outP[mi], b1 = outB[mi], d1 = outD[mi];
    float p2 = outP[pi], b2 = outB[pi], d2 = outD[pi];
    bool h1 = p1 > 0.f, h2 = p2 > 0.f;
    float cost = 0.f;
    if (h1 && h2)      cost = (b1 - b2) * (b1 - b2) + (d1 - d2) * (d1 - d2);
    else if (h1)       cost = p1 * p1 * 0.5f;
    else if (h2)       cost = p2 * p2 * 0.5f;

    for (int off = 32; off > 0; off >>= 1) cost += __shfl_down(cost, off);
    __shared__ float part[16];
    __shared__ float dist[4];
    int wv = tid >> 6;
    if ((tid & 63) == 0) part[wv] = cost;
    __syncthreads();
    if (tid < 4) {
        float sum = part[tid * 4] + part[tid * 4 + 1] + part[tid * 4 + 2] + part[tid * 4 + 3];
        dist[tid] = sqrtf(sum + 1e-12f);
    }
    __syncthreads();
    if (tid == 0)
        out[0] = 0.01f * (dist[0] + dist[1] + dist[2] + dist[3]) / 4.0f;
}

// ws layout (bytes):
//   lvl  u8 [8][16384]          @ 0        (131072)
//   maxL i32[8]                 @ 131072   (32)
//   argmin u32[8]               @ 131104   (32)
//   bits u64[8][11][256]        @ 131136   (180224)
//   outP/outB/outD f32[8][256]  @ 311360   (24576)
extern "C" void kernel_launch(void* const* d_in, const int* in_sizes, int n_in,
                              void* d_out, int out_size, void* d_ws, size_t ws_size,
                              hipStream_t stream)
{
    const float* model_output = (const float*)d_in[0];
    const float* labels = (const float*)d_in[1];
    char* ws = (char*)d_ws;
    uint8_t* lvl = (uint8_t*)ws;
    int* maxL = (int*)(ws + 131072);
    unsigned* argmin = (unsigned*)(ws + 131104);
    unsigned long long* bits = (unsigned long long*)(ws + 131136);
    float* outP = (float*)(ws + 311360);
    float* outB = outP + NIMG * 256;
    float* outD = outB + NIMG * 256;
    float* out = (float*)d_out;

    prep_kernel<<<NIMG, 1024, 0, stream>>>(model_output, labels, lvl, maxL, argmin);
    ccl_kernel<<<NIMG * NLVL, 1024, 0, stream>>>(lvl, maxL, argmin, bits);
    death_kernel<<<NIMG, 1024, 0, stream>>>(lvl, maxL, bits, outP, outB, outD);
    wdist_kernel<<<1, 1024, 0, stream>>>(outP, outB, outD, out);
}

// Round 7
// 147.963 us; speedup vs baseline: 1.7476x; 1.7476x over previous
//
#include <hip/hip_runtime.h>
#include <stdint.h>

#define NPIX 16384
#define IMW 128
#define NIMG 8
#define NLVL 11
#define BIGK 0xFFFFFFFFu
#define IMASK 16383u
#define DONE 0x0D0E0D0Eu   // != 0xAAAAAAAA ws-poison, so flags need no init

// ---------------- union-find (u16 parents in LDS) — round-5 verified ----------------
// Parent keys ((lvl<<14)|idx) strictly decrease along links -> acyclic.
// Path-halving writes are benign races (only ever install an ancestor).
__device__ __forceinline__ unsigned find16(volatile unsigned short* par, unsigned i) {
    unsigned j = par[i];
    while (j != i) {
        unsigned pj = par[j];
        if (pj == j) return j;
        par[i] = (unsigned short)pj;
        i = j; j = pj;
    }
    return i;
}

// union by key; smaller key (elder) wins. u16 parent CAS'd through its u32 word.
__device__ __forceinline__ void union16(volatile unsigned short* par, unsigned* par32,
                                        const uint8_t* lvl, unsigned a, unsigned b) {
    unsigned ra = find16(par, a);
    unsigned rb = find16(par, b);
    while (ra != rb) {
        unsigned ka = ((unsigned)lvl[ra] << 14) | ra;
        unsigned kb = ((unsigned)lvl[rb] << 14) | rb;
        unsigned hi = (ka > kb) ? ra : rb;   // younger root: absorbed
        unsigned lo = (ka > kb) ? rb : ra;   // elder root: survives
        unsigned w = hi >> 1, sh = (hi & 1u) * 16u;
        unsigned old32 = ((volatile unsigned*)par32)[w];
        if (((old32 >> sh) & 0xFFFFu) == hi) {
            unsigned new32 = (old32 & ~(0xFFFFu << sh)) | (lo << sh);
            if (atomicCAS(par32 + w, old32, new32) == old32) return;
        }
        ra = find16(par, hi);
        rb = find16(par, lo);
    }
}

// ---------------- inter-block release/acquire flags ----------------
__device__ __forceinline__ void flag_release(unsigned* p) {
    __threadfence();
    __hip_atomic_store(p, DONE, __ATOMIC_RELEASE, __HIP_MEMORY_SCOPE_AGENT);
}
__device__ __forceinline__ void flag_acquire(unsigned* p) {
    while (__hip_atomic_load(p, __ATOMIC_ACQUIRE, __HIP_MEMORY_SCOPE_AGENT) != DONE)
        __builtin_amdgcn_s_sleep(2);
}

// ---------------- one fused kernel: 8 prep + 88 ccl + 8 death + 1 wdist blocks ----
// All 105 blocks co-resident (<=256 CUs); producers have lower block IDs.
// Dependencies via magic-value flags: prep[img] -> ccl[img][l] -> death[img] -> wdist.
__global__ __launch_bounds__(1024) void topo_fused(const float* __restrict__ model_output,
                                                   const float* __restrict__ labels,
                                                   uint8_t* __restrict__ lvl_all,
                                                   int* __restrict__ maxL_all,
                                                   unsigned* __restrict__ argmin_all,
                                                   unsigned long long* __restrict__ bits_all,
                                                   float* __restrict__ outP,
                                                   float* __restrict__ outB,
                                                   float* __restrict__ outD,
                                                   unsigned* __restrict__ flags,
                                                   float* __restrict__ out)
{
    __shared__ __align__(16) unsigned char smem[60416];   // aliased per role (max = death)
    int blk = blockIdx.x;
    int tid = threadIdx.x;
    unsigned lane = tid & 63u;

    if (blk < 8) {
        // ================= prep: sigmoid/normalize/quantize, one block/image ======
        int img = blk;
        bool ismask = img < 4;
        const float* src = ismask ? (labels + (size_t)img * NPIX)
                                  : (model_output + (size_t)(img - 4) * NPIX);
        uint8_t* lvl = lvl_all + (size_t)img * NPIX;
        float* s_f = (float*)smem;                 // [32]
        unsigned* s_u = (unsigned*)(smem + 128);   // [32]
        float* s_mnmx = (float*)(smem + 256);      // [2]

        float mn = 0.f, mx = 1.f;
        if (!ismask) {
            float lmn = 1e30f, lmx = -1e30f;
            for (int i = tid; i < NPIX; i += 1024) {
                float s = 1.0f / (1.0f + expf(-src[i]));
                lmn = fminf(lmn, s); lmx = fmaxf(lmx, s);
            }
            for (int off = 32; off > 0; off >>= 1) {
                lmn = fminf(lmn, __shfl_down(lmn, off));
                lmx = fmaxf(lmx, __shfl_down(lmx, off));
            }
            int wv = tid >> 6;
            if (lane == 0) { s_f[wv] = lmn; s_f[16 + wv] = lmx; }
            __syncthreads();
            if (tid == 0) {
                float a = s_f[0], c = s_f[16];
                for (int w = 1; w < 16; ++w) { a = fminf(a, s_f[w]); c = fmaxf(c, s_f[16 + w]); }
                s_mnmx[0] = a; s_mnmx[1] = c;
            }
            __syncthreads();
            mn = s_mnmx[0]; mx = s_mnmx[1];
        }
        float denom = mx - mn;
        if (denom <= 0.f) denom = 1.f;

        unsigned lmaxk = 0, bestk = BIGK;
        for (int i = tid; i < NPIX; i += 1024) {
            int L;
            if (ismask) L = (int)rintf(src[i] * 10.0f);
            else {
                float s = 1.0f / (1.0f + expf(-src[i]));
                L = (int)rintf((s - mn) / denom * 10.0f);
            }
            lvl[i] = (uint8_t)L;
            unsigned key = ((unsigned)L << 14) | (unsigned)i;
            lmaxk = max(lmaxk, (unsigned)L);
            bestk = min(bestk, key);
        }
        for (int off = 32; off > 0; off >>= 1) {
            lmaxk = max(lmaxk, (unsigned)__shfl_down((int)lmaxk, off));
            bestk = min(bestk, (unsigned)__shfl_down((int)bestk, off));
        }
        if (lane == 0) { s_u[tid >> 6] = lmaxk; s_u[16 + (tid >> 6)] = bestk; }
        __syncthreads();
        if (tid == 0) {
            unsigned m = s_u[0], b = s_u[16];
            for (int w = 1; w < 16; ++w) { m = max(m, s_u[w]); b = min(b, s_u[16 + w]); }
            maxL_all[img] = (int)m;
            argmin_all[img] = b & IMASK;
            flag_release(&flags[img]);
        }
        return;
    }

    if (blk < 96) {
        // ================= ccl: one block per (image, threshold) ==================
        int b = blk - 8;
        int img = b / NLVL, l = b % NLVL;
        int w = tid >> 6;                          // wave id == 8-row strip id
        uint8_t* s_lvl = (uint8_t*)smem;                       // 16384
        unsigned* s_par32 = (unsigned*)(smem + 16384);         // 32768
        volatile unsigned short* par = (volatile unsigned short*)s_par32;
        unsigned long long* bits = bits_all + ((size_t)img * NLVL + l) * 256;

        if (tid == 0) flag_acquire(&flags[img]);
        __syncthreads();
        int maxL = maxL_all[img];

        if (l >= maxL) {   // whole grid one component: root = precomputed argmin
            unsigned win = argmin_all[img];
            for (int q = tid; q < 256; q += 1024)
                bits[q] = ((win >> 6) == (unsigned)q) ? (1ull << (win & 63u)) : 0ull;
            __syncthreads();
            if (tid == 0) flag_release(&flags[8 + b]);
            return;
        }

        ((uint4*)s_lvl)[tid] = ((const uint4*)(lvl_all + (size_t)img * NPIX))[tid];
        __syncthreads();

        // ---- Phase A: horizontal runs -> parent = run min-key (ballot + seg scan).
        // Strip indexing: i = w*1024 + k*64 + lane; each (w,k) is one 64-px segment,
        // rows = 2 segments, so segments never straddle rows.
#pragma unroll
        for (int k = 0; k < 16; ++k) {
            int i = (w << 10) + (k << 6) + (int)lane;
            uint8_t Lv = s_lvl[i];
            bool act = (int)Lv <= l;
            unsigned long long m = __ballot(act);
            unsigned key = act ? (((unsigned)Lv << 14) | (unsigned)i) : BIGK;
            unsigned long long lowmask = (1ull << lane) - 1ull;
            unsigned long long zb = (~m) & lowmask;
            int runstart = zb ? (64 - __clzll(zb)) : 0;
            unsigned v = key;
#pragma unroll
            for (int d = 1; d < 64; d <<= 1) {
                unsigned o = __shfl_up(v, d, 64);
                if ((int)lane - d >= runstart) v = min(v, o);
            }
            unsigned long long za = (lane == 63u) ? 0ull : ((~m) >> (lane + 1));
            int runend = za ? ((int)lane + __ffsll((long long)za) - 1) : 63;
            unsigned rmin = __shfl(v, runend, 64);
            par[i] = (unsigned short)(act ? (rmin & IMASK) : (unsigned)i);
        }

        // ---- Phase B1: intra-strip unions (own-wave LDS only -> no barrier needed).
        // Seam edges (col 64) for all rows; vertical edges for rows 1..7 of strip.
        // Dedup: skip vertical union unless leftmost pixel of the run-pair overlap.
#pragma unroll
        for (int k = 0; k < 16; ++k) {
            int i = (w << 10) + (k << 6) + (int)lane;
            if (s_lvl[i] > l) continue;
            if ((k & 1) && lane == 0u && s_lvl[i - 1] <= l)
                union16(par, s_par32, s_lvl, (unsigned)i, (unsigned)(i - 1));
            if (k >= 2 && s_lvl[i - IMW] <= l) {
                int col = ((k & 1) << 6) + (int)lane;
                bool leftpair = (col != 0) && (s_lvl[i - 1] <= l) && (s_lvl[i - 1 - IMW] <= l);
                if (!leftpair)
                    union16(par, s_par32, s_lvl, (unsigned)i, (unsigned)(i - IMW));
            }
        }
        __syncthreads();

        // ---- Phase B2: inter-strip boundary rows (first row of strips 1..15) ----
        if (w >= 1) {
#pragma unroll
            for (int k = 0; k < 2; ++k) {
                int i = (w << 10) + (k << 6) + (int)lane;
                if (s_lvl[i] <= l && s_lvl[i - IMW] <= l) {
                    int col = (k << 6) + (int)lane;
                    bool leftpair = (col != 0) && (s_lvl[i - 1] <= l) && (s_lvl[i - 1 - IMW] <= l);
                    if (!leftpair)
                        union16(par, s_par32, s_lvl, (unsigned)i, (unsigned)(i - IMW));
                }
            }
        }
        __syncthreads();

        // ---- emit root bitmap (root <=> par fixed point) ----
#pragma unroll
        for (int k = 0; k < 16; ++k) {
            int i = (w << 10) + (k << 6) + (int)lane;
            bool isroot = (s_lvl[i] <= l) && (par[i] == (unsigned short)i);
            unsigned long long m = __ballot(isroot);
            if (lane == 0u) bits[i >> 6] = m;
        }
        __syncthreads();
        if (tid == 0) flag_release(&flags[8 + b]);
        return;
    }

    if (blk < 104) {
        // ================= death: deaths from bitmaps + top-256, one block/image ==
        int img = blk - 96;
        unsigned long long* s_bits = (unsigned long long*)smem;          // [11][256] 22528
        uint8_t*  s_lvl  = (uint8_t*)(smem + 22528);                     // 16384
        uint8_t*  s_rank = (uint8_t*)(smem + 38912);                     // 16384
        unsigned long long* s_bm = (unsigned long long*)(smem + 55296);  // [256] 2048
        unsigned* s_keys = (unsigned*)(smem + 57344);                    // [256]
        unsigned* s_pc   = (unsigned*)(smem + 58368);                    // [256]
        unsigned* s_hist = (unsigned*)(smem + 59392);                    // [64]
        uint8_t*  s_rtab = (uint8_t*)(smem + 59648);                     // [121]
        unsigned* s_ctl  = (unsigned*)(smem + 59776);                    // [4]

        if (tid < NLVL) flag_acquire(&flags[8 + img * NLVL + tid]);
        __syncthreads();

        const uint8_t* lv = lvl_all + (size_t)img * NPIX;
        const unsigned long long* gbits = bits_all + (size_t)img * NLVL * 256;
        int maxL = maxL_all[img];

        for (int q = tid; q < NLVL * 256; q += 1024) s_bits[q] = gbits[q];
        ((uint4*)s_lvl)[tid] = ((const uint4*)lv)[tid];
        if (tid < 64) s_hist[tid] = 0;
        if (tid < 256) { s_bm[tid] = 0ull; s_keys[tid] = 0xFFFFFFFFu; }
        // rank(d,b) = #(of 55 (dd,bb) pairs) with strictly larger f32 pers;
        // order-isomorphic to float ordering; equal floats share rank -> tie by idx.
        if (tid < NLVL * NLVL) {
            int d = tid / NLVL, bb0 = tid % NLVL;
            if (d > bb0) {
                float pers = (float)d / 10.0f - (float)bb0 / 10.0f;
                unsigned rk = 0;
                for (int dd = 1; dd <= 10; ++dd)
                    for (int bb = 0; bb < dd; ++bb) {
                        float pp = (float)dd / 10.0f - (float)bb / 10.0f;
                        rk += (pp > pers) ? 1u : 0u;
                    }
                s_rtab[d * NLVL + bb0] = (uint8_t)rk;
            }
        }
        __syncthreads();

        // pass 1: candidates, ranks, histogram
        for (int i = tid; i < NPIX; i += 1024) {
            uint8_t r = 0xFF;
            int b = s_lvl[i];
            if ((s_bits[b * 256 + (i >> 6)] >> (i & 63)) & 1ull) {
                int d = maxL;
                for (int l = b + 1; l <= maxL; ++l)
                    if (!((s_bits[l * 256 + (i >> 6)] >> (i & 63)) & 1ull)) { d = l; break; }
                if (d > b) { r = s_rtab[d * NLVL + b]; atomicAdd(&s_hist[r], 1u); }
            }
            s_rank[i] = r;
        }
        __syncthreads();

        if (tid == 0) {
            unsigned cum = 0, rstar = 63, cless = 0;
            for (int r = 0; r < 56; ++r) {
                if (cum + s_hist[r] >= 256u && rstar == 63u) { rstar = r; cless = cum; }
                cum += s_hist[r];
            }
            if (rstar == 63u) cless = cum;
            s_ctl[0] = rstar; s_ctl[1] = cless;
            s_ctl[2] = (rstar == 63u) ? 0u : (256u - cless);
            s_ctl[3] = 0;
        }
        __syncthreads();
        unsigned rstar = s_ctl[0], cless = s_ctl[1], mneed = s_ctl[2];

        // pass 2: compact rank<r*; bitmap for rank==r*
        for (int i = tid; i < NPIX; i += 1024) {
            unsigned r = s_rank[i];
            if (r == 0xFFu) continue;
            if (r < rstar) {
                unsigned pos = atomicAdd(&s_ctl[3], 1u);
                if (pos < 256u) s_keys[pos] = (r << 14) | (unsigned)i;
            } else if (r == rstar) {
                atomicOr(&s_bm[i >> 6], 1ull << (i & 63));
            }
        }
        __syncthreads();

        // bitonic sort 256 keys ascending == (rank asc, idx asc)
        for (unsigned kk = 2; kk <= 256; kk <<= 1) {
            for (unsigned j = kk >> 1; j > 0; j >>= 1) {
                if (tid < 256) {
                    unsigned i = (unsigned)tid, ixj = i ^ j;
                    if (ixj > i) {
                        unsigned x = s_keys[i], y = s_keys[ixj];
                        bool up = ((i & kk) == 0);
                        if ((x > y) == up) { s_keys[i] = y; s_keys[ixj] = x; }
                    }
                }
                __syncthreads();
            }
        }

        // bucket r*: popcount-prefix -> each member computes its slot
        if (tid < 256) s_pc[tid] = (unsigned)__popcll(s_bm[tid]);
        __syncthreads();
        for (int d = 1; d < 256; d <<= 1) {
            unsigned x = 0;
            if (tid < 256 && tid >= d) x = s_pc[tid - d];
            __syncthreads();
            if (tid < 256 && tid >= d) s_pc[tid] += x;
            __syncthreads();
        }
        for (int i = tid; i < NPIX; i += 1024) {
            if (s_rank[i] != rstar || rstar == 63u) continue;
            if (!((s_bm[i >> 6] >> (i & 63)) & 1ull)) continue;
            unsigned w = i >> 6;
            unsigned order = (w ? s_pc[w - 1] : 0u)
                           + (unsigned)__popcll(s_bm[w] & ((1ull << (i & 63)) - 1ull));
            if (order < mneed) s_keys[cless + order] = (rstar << 14) | (unsigned)i;
        }
        __syncthreads();

        for (int s = tid; s < 256; s += 1024) {
            unsigned key = s_keys[s];
            float p = 0.f, bv = 0.f, dv = 0.f;
            if (key != 0xFFFFFFFFu) {
                unsigned i = key & IMASK;
                int b = s_lvl[i];
                int d = maxL;
                for (int l = b + 1; l <= maxL; ++l)
                    if (!((s_bits[l * 256 + (i >> 6)] >> (i & 63)) & 1ull)) { d = l; break; }
                bv = (float)b / 10.0f;
                dv = (float)d / 10.0f;
                p = dv - bv;
            }
            outP[img * 256 + s] = p;
            outB[img * 256 + s] = bv;
            outD[img * 256 + s] = dv;
        }
        __syncthreads();
        if (tid == 0) flag_release(&flags[96 + img]);
        return;
    }

    // ================= wdist: matching + final loss, one block =================
    {
        if (tid < 8) flag_acquire(&flags[96 + tid]);
        __syncthreads();

        float* part = (float*)smem;          // [16]
        float* dist = (float*)(smem + 64);   // [4]
        int s = tid >> 8;
        int slot = tid & 255;
        int mi = s * 256 + slot;
        int pi = (4 + s) * 256 + slot;
        float p1 = outP[mi], b1 = outB[mi], d1 = outD[mi];
        float p2 = outP[pi], b2 = outB[pi], d2 = outD[pi];
        bool h1 = p1 > 0.f, h2 = p2 > 0.f;
        float cost = 0.f;
        if (h1 && h2)      cost = (b1 - b2) * (b1 - b2) + (d1 - d2) * (d1 - d2);
        else if (h1)       cost = p1 * p1 * 0.5f;
        else if (h2)       cost = p2 * p2 * 0.5f;

        for (int off = 32; off > 0; off >>= 1) cost += __shfl_down(cost, off);
        int wv = tid >> 6;
        if (lane == 0u) part[wv] = cost;
        __syncthreads();
        if (tid < 4) {
            float sum = part[tid * 4] + part[tid * 4 + 1] + part[tid * 4 + 2] + part[tid * 4 + 3];
            dist[tid] = sqrtf(sum + 1e-12f);
        }
        __syncthreads();
        if (tid == 0)
            out[0] = 0.01f * (dist[0] + dist[1] + dist[2] + dist[3]) / 4.0f;
    }
}

// ws layout (bytes):
//   lvl  u8 [8][16384]          @ 0        (131072)
//   maxL i32[8]                 @ 131072   (32)
//   argmin u32[8]               @ 131104   (32)
//   bits u64[8][11][256]        @ 131136   (180224)
//   outP/outB/outD f32[8][256]  @ 311360   (24576)
//   flags u32[104]              @ 335936   (416)
extern "C" void kernel_launch(void* const* d_in, const int* in_sizes, int n_in,
                              void* d_out, int out_size, void* d_ws, size_t ws_size,
                              hipStream_t stream)
{
    const float* model_output = (const float*)d_in[0];
    const float* labels = (const float*)d_in[1];
    char* ws = (char*)d_ws;
    uint8_t* lvl = (uint8_t*)ws;
    int* maxL = (int*)(ws + 131072);
    unsigned* argmin = (unsigned*)(ws + 131104);
    unsigned long long* bits = (unsigned long long*)(ws + 131136);
    float* outP = (float*)(ws + 311360);
    float* outB = outP + NIMG * 256;
    float* outD = outB + NIMG * 256;
    unsigned* flags = (unsigned*)(ws + 335936);
    float* out = (float*)d_out;

    topo_fused<<<105, 1024, 0, stream>>>(model_output, labels, lvl, maxL, argmin,
                                         bits, outP, outB, outD, flags, out);
}

// Round 8
// 141.618 us; speedup vs baseline: 1.8259x; 1.0448x over previous
//
#include <hip/hip_runtime.h>
#include <stdint.h>

#define NPIX 16384
#define IMW 128
#define NIMG 8
#define NLVL 11
#define BIGK 0xFFFFFFFFu
#define IMASK 16383u
#define DONE 0x0D0E0D0Eu   // != 0xAAAAAAAA ws-poison, so flags need no init

// ---------------- union-find (u16 parents in LDS) — verified r5/r7 ----------------
__device__ __forceinline__ unsigned find16(volatile unsigned short* par, unsigned i) {
    unsigned j = par[i];
    while (j != i) {
        unsigned pj = par[j];
        if (pj == j) return j;
        par[i] = (unsigned short)pj;   // path halving: benign race, installs ancestor
        i = j; j = pj;
    }
    return i;
}

__device__ __forceinline__ void union16(volatile unsigned short* par, unsigned* par32,
                                        const uint8_t* lvl, unsigned a, unsigned b) {
    unsigned ra = find16(par, a);
    unsigned rb = find16(par, b);
    while (ra != rb) {
        unsigned ka = ((unsigned)lvl[ra] << 14) | ra;
        unsigned kb = ((unsigned)lvl[rb] << 14) | rb;
        unsigned hi = (ka > kb) ? ra : rb;   // younger root: absorbed
        unsigned lo = (ka > kb) ? rb : ra;   // elder root: survives
        unsigned w = hi >> 1, sh = (hi & 1u) * 16u;
        unsigned old32 = ((volatile unsigned*)par32)[w];
        if (((old32 >> sh) & 0xFFFFu) == hi) {
            unsigned new32 = (old32 & ~(0xFFFFu << sh)) | (lo << sh);
            if (atomicCAS(par32 + w, old32, new32) == old32) return;
        }
        ra = find16(par, hi);
        rb = find16(par, lo);
    }
}

__device__ __forceinline__ void flag_release(unsigned* p) {
    __threadfence();
    __hip_atomic_store(p, DONE, __ATOMIC_RELEASE, __HIP_MEMORY_SCOPE_AGENT);
}
__device__ __forceinline__ void flag_acquire(unsigned* p) {
    while (__hip_atomic_load(p, __ATOMIC_ACQUIRE, __HIP_MEMORY_SCOPE_AGENT) != DONE)
        __builtin_amdgcn_s_sleep(2);
}

// ================= dispatch A: 8 prep blocks + 88 ccl blocks =================
// prep[img] quantizes + zeroes rootmask[img], then releases flags[img].
// ccl[(img,l)] waits on flags[img], does strip CCL, atomicOr's root bits.
__global__ __launch_bounds__(1024) void prep_ccl(const float* __restrict__ model_output,
                                                 const float* __restrict__ labels,
                                                 uint8_t* __restrict__ lvl_all,
                                                 int* __restrict__ maxL_all,
                                                 unsigned* __restrict__ argmin_all,
                                                 unsigned* __restrict__ rootmask_all,
                                                 unsigned* __restrict__ flags)
{
    __shared__ __align__(16) unsigned char smem[49152];
    int blk = blockIdx.x;
    int tid = threadIdx.x;
    unsigned lane = tid & 63u;

    if (blk < 8) {
        // ---- prep: sigmoid/normalize/quantize, one block per image ----
        int img = blk;
        bool ismask = img < 4;
        const float* src = ismask ? (labels + (size_t)img * NPIX)
                                  : (model_output + (size_t)(img - 4) * NPIX);
        uint8_t* lvl = lvl_all + (size_t)img * NPIX;
        unsigned* rm = rootmask_all + (size_t)img * NPIX;
        float* s_f = (float*)smem;                 // [32]
        unsigned* s_u = (unsigned*)(smem + 128);   // [32]
        float* s_mnmx = (float*)(smem + 256);      // [2]

        // zero rootmask for this image (ws is poisoned 0xAA)
        for (int q = tid; q < NPIX / 4; q += 1024)
            ((uint4*)rm)[q] = make_uint4(0, 0, 0, 0);

        float mn = 0.f, mx = 1.f;
        if (!ismask) {
            float lmn = 1e30f, lmx = -1e30f;
            for (int i = tid; i < NPIX; i += 1024) {
                float s = 1.0f / (1.0f + expf(-src[i]));
                lmn = fminf(lmn, s); lmx = fmaxf(lmx, s);
            }
            for (int off = 32; off > 0; off >>= 1) {
                lmn = fminf(lmn, __shfl_down(lmn, off));
                lmx = fmaxf(lmx, __shfl_down(lmx, off));
            }
            int wv = tid >> 6;
            if (lane == 0) { s_f[wv] = lmn; s_f[16 + wv] = lmx; }
            __syncthreads();
            if (tid == 0) {
                float a = s_f[0], c = s_f[16];
                for (int w = 1; w < 16; ++w) { a = fminf(a, s_f[w]); c = fmaxf(c, s_f[16 + w]); }
                s_mnmx[0] = a; s_mnmx[1] = c;
            }
            __syncthreads();
            mn = s_mnmx[0]; mx = s_mnmx[1];
        }
        float denom = mx - mn;
        if (denom <= 0.f) denom = 1.f;

        unsigned lmaxk = 0, bestk = BIGK;
        for (int i = tid; i < NPIX; i += 1024) {
            int L;
            if (ismask) L = (int)rintf(src[i] * 10.0f);
            else {
                float s = 1.0f / (1.0f + expf(-src[i]));
                L = (int)rintf((s - mn) / denom * 10.0f);
            }
            lvl[i] = (uint8_t)L;
            unsigned key = ((unsigned)L << 14) | (unsigned)i;
            lmaxk = max(lmaxk, (unsigned)L);
            bestk = min(bestk, key);
        }
        for (int off = 32; off > 0; off >>= 1) {
            lmaxk = max(lmaxk, (unsigned)__shfl_down((int)lmaxk, off));
            bestk = min(bestk, (unsigned)__shfl_down((int)bestk, off));
        }
        if (lane == 0) { s_u[tid >> 6] = lmaxk; s_u[16 + (tid >> 6)] = bestk; }
        __syncthreads();
        if (tid == 0) {
            unsigned m = s_u[0], b = s_u[16];
            for (int w = 1; w < 16; ++w) { m = max(m, s_u[w]); b = min(b, s_u[16 + w]); }
            maxL_all[img] = (int)m;
            argmin_all[img] = b & IMASK;
            flag_release(&flags[img]);
        }
        return;
    }

    // ---- ccl: one block per (image, threshold); wave w owns rows [8w, 8w+8) ----
    int b = blk - 8;
    int img = b / NLVL, l = b % NLVL;
    int w = tid >> 6;
    uint8_t* s_lvl = (uint8_t*)smem;                  // 16384
    unsigned* s_par32 = (unsigned*)(smem + 16384);    // 32768
    volatile unsigned short* par = (volatile unsigned short*)s_par32;
    unsigned* rm = rootmask_all + (size_t)img * NPIX;

    if (tid == 0) flag_acquire(&flags[img]);
    __syncthreads();
    int maxL = maxL_all[img];

    if (l >= maxL) {   // whole grid one component: single root = precomputed argmin
        if (tid == 0) atomicOr(&rm[argmin_all[img]], 1u << l);
        return;
    }

    ((uint4*)s_lvl)[tid] = ((const uint4*)(lvl_all + (size_t)img * NPIX))[tid];
    __syncthreads();

    // ---- Phase A: horizontal runs -> parent = run min-key (ballot + seg scan).
    // i = w*1024 + k*64 + lane; each (w,k) is one 64-px segment (rows = 2 segs).
    unsigned am = 0;   // activity mask, bit k
#pragma unroll
    for (int k = 0; k < 16; ++k) {
        int i = (w << 10) + (k << 6) + (int)lane;
        uint8_t Lv = s_lvl[i];
        bool act = (int)Lv <= l;
        if (act) am |= 1u << k;
        unsigned long long m = __ballot(act);
        unsigned key = act ? (((unsigned)Lv << 14) | (unsigned)i) : BIGK;
        unsigned long long lowmask = (1ull << lane) - 1ull;
        unsigned long long zb = (~m) & lowmask;
        int runstart = zb ? (64 - __clzll(zb)) : 0;
        unsigned v = key;
#pragma unroll
        for (int d = 1; d < 64; d <<= 1) {
            unsigned o = __shfl_up(v, d, 64);
            if ((int)lane - d >= runstart) v = min(v, o);
        }
        unsigned long long za = (lane == 63u) ? 0ull : ((~m) >> (lane + 1));
        int runend = za ? ((int)lane + __ffsll((long long)za) - 1) : 63;
        unsigned rmin = __shfl(v, runend, 64);
        par[i] = (unsigned short)(act ? (rmin & IMASK) : (unsigned)i);
    }

    unsigned amL  = (unsigned)__shfl_up((int)am, 1, 64);   // lane-1's mask (junk on lane 0)
    unsigned am63 = (unsigned)__shfl((int)am, 63, 64);     // lane 63's mask

    // ---- Phase B1: intra-strip unions (register guards; own-wave LDS only).
    // Duplicate unions are no-ops; all ambiguous dedup cases fall back to union.
#pragma unroll
    for (int k = 0; k < 16; ++k) {
        if (!((am >> k) & 1u)) continue;
        int i = (w << 10) + (k << 6) + (int)lane;
        if ((k & 1) && lane == 0u && ((am63 >> (k - 1)) & 1u))   // seam: run crosses col 64
            union16(par, s_par32, s_lvl, (unsigned)i, (unsigned)(i - 1));
        if (k >= 2 && ((am >> (k - 2)) & 1u)) {                  // vertical within strip
            bool leftpair = (lane > 0u) && ((amL >> k) & 1u) && ((amL >> (k - 2)) & 1u);
            if (!leftpair)
                union16(par, s_par32, s_lvl, (unsigned)i, (unsigned)(i - IMW));
        }
    }
    __syncthreads();

    // ---- Phase B2: inter-strip boundary (first row of strips 1..15) ----
    if (w >= 1) {
#pragma unroll
        for (int k = 0; k < 2; ++k) {
            if (!((am >> k) & 1u)) continue;
            int i = (w << 10) + (k << 6) + (int)lane;
            if (s_lvl[i - IMW] <= l) {
                int col = (k << 6) + (int)lane;
                bool lact = (lane > 0u) ? (((amL >> k) & 1u) != 0u)
                                        : (k == 1 ? (((am63 >> 0) & 1u) != 0u) : false);
                bool leftpair = (col != 0) && lact && (s_lvl[i - 1 - IMW] <= l);
                if (!leftpair)
                    union16(par, s_par32, s_lvl, (unsigned)i, (unsigned)(i - IMW));
            }
        }
    }
    __syncthreads();

    // ---- emit: root pixels set bit l in rootmask (sparse) ----
#pragma unroll
    for (int k = 0; k < 16; ++k) {
        if (!((am >> k) & 1u)) continue;
        int i = (w << 10) + (k << 6) + (int)lane;
        if (par[i] == (unsigned short)i) atomicOr(&rm[i], 1u << l);
    }
}

// ================= dispatch B: deaths + top-256, one block per image =========
__global__ __launch_bounds__(1024) void death_kernel(const uint8_t* __restrict__ lvl_all,
                                                     const int* __restrict__ maxL_all,
                                                     const unsigned* __restrict__ rootmask_all,
                                                     float* __restrict__ outP,
                                                     float* __restrict__ outB,
                                                     float* __restrict__ outD)
{
    __shared__ uint8_t  s_lvl[NPIX];
    __shared__ uint8_t  s_rank[NPIX];
    __shared__ unsigned long long s_bm[256];
    __shared__ unsigned s_keys[256];
    __shared__ unsigned s_pc[256];
    __shared__ unsigned s_hist[64];
    __shared__ uint8_t  s_rtab[NLVL * NLVL];
    __shared__ unsigned s_ctl[4];

    int img = blockIdx.x;
    int tid = threadIdx.x;
    const uint8_t* lv = lvl_all + (size_t)img * NPIX;
    const unsigned* rmg = rootmask_all + (size_t)img * NPIX;
    int maxL = maxL_all[img];

    ((uint4*)s_lvl)[tid] = ((const uint4*)lv)[tid];
    if (tid < 64) s_hist[tid] = 0;
    if (tid < 256) { s_bm[tid] = 0ull; s_keys[tid] = 0xFFFFFFFFu; }
    // rank(d,b) = #(of 55 (dd,bb) pairs) with strictly larger f32 pers;
    // order-isomorphic to float ordering; equal floats share rank -> tie by idx.
    if (tid < NLVL * NLVL) {
        int d = tid / NLVL, bb0 = tid % NLVL;
        if (d > bb0) {
            float pers = (float)d / 10.0f - (float)bb0 / 10.0f;
            unsigned rk = 0;
            for (int dd = 1; dd <= 10; ++dd)
                for (int bb = 0; bb < dd; ++bb) {
                    float pp = (float)dd / 10.0f - (float)bb / 10.0f;
                    rk += (pp > pers) ? 1u : 0u;
                }
            s_rtab[d * NLVL + bb0] = (uint8_t)rk;
        }
    }
    __syncthreads();

    // pass 1: candidate iff root at birth level; death = first clear bit above b
    for (int i = tid; i < NPIX; i += 1024) {
        uint8_t r = 0xFF;
        int b = s_lvl[i];
        unsigned rmv = rmg[i];
        if ((rmv >> b) & 1u) {
            unsigned inv = (~rmv) >> (b + 1);          // bits >= 11 of ~rmv are set -> inv != 0
            int d = b + 1 + (__ffs(inv) - 1);
            d = min(d, maxL);                          // all-set through maxL -> essential
            if (d > b) { r = s_rtab[d * NLVL + b]; atomicAdd(&s_hist[r], 1u); }
        }
        s_rank[i] = r;
    }
    __syncthreads();

    if (tid == 0) {
        unsigned cum = 0, rstar = 63, cless = 0;
        for (int r = 0; r < 56; ++r) {
            if (cum + s_hist[r] >= 256u && rstar == 63u) { rstar = r; cless = cum; }
            cum += s_hist[r];
        }
        if (rstar == 63u) cless = cum;
        s_ctl[0] = rstar; s_ctl[1] = cless;
        s_ctl[2] = (rstar == 63u) ? 0u : (256u - cless);
        s_ctl[3] = 0;
    }
    __syncthreads();
    unsigned rstar = s_ctl[0], cless = s_ctl[1], mneed = s_ctl[2];

    // pass 2: compact rank<r*; bitmap for rank==r*
    for (int i = tid; i < NPIX; i += 1024) {
        unsigned r = s_rank[i];
        if (r == 0xFFu) continue;
        if (r < rstar) {
            unsigned pos = atomicAdd(&s_ctl[3], 1u);
            if (pos < 256u) s_keys[pos] = (r << 14) | (unsigned)i;
        } else if (r == rstar) {
            atomicOr(&s_bm[i >> 6], 1ull << (i & 63));
        }
    }
    __syncthreads();

    // bitonic sort 256 keys ascending == (rank asc, idx asc)
    for (unsigned kk = 2; kk <= 256; kk <<= 1) {
        for (unsigned j = kk >> 1; j > 0; j >>= 1) {
            if (tid < 256) {
                unsigned i = (unsigned)tid, ixj = i ^ j;
                if (ixj > i) {
                    unsigned x = s_keys[i], y = s_keys[ixj];
                    bool up = ((i & kk) == 0);
                    if ((x > y) == up) { s_keys[i] = y; s_keys[ixj] = x; }
                }
            }
            __syncthreads();
        }
    }

    // bucket r*: popcount-prefix -> each member computes its slot
    if (tid < 256) s_pc[tid] = (unsigned)__popcll(s_bm[tid]);
    __syncthreads();
    for (int d = 1; d < 256; d <<= 1) {
        unsigned x = 0;
        if (tid < 256 && tid >= d) x = s_pc[tid - d];
        __syncthreads();
        if (tid < 256 && tid >= d) s_pc[tid] += x;
        __syncthreads();
    }
    for (int i = tid; i < NPIX; i += 1024) {
        if (s_rank[i] != rstar || rstar == 63u) continue;
        if (!((s_bm[i >> 6] >> (i & 63)) & 1ull)) continue;
        unsigned w = i >> 6;
        unsigned order = (w ? s_pc[w - 1] : 0u)
                       + (unsigned)__popcll(s_bm[w] & ((1ull << (i & 63)) - 1ull));
        if (order < mneed) s_keys[cless + order] = (rstar << 14) | (unsigned)i;
    }
    __syncthreads();

    for (int s = tid; s < 256; s += 1024) {
        unsigned key = s_keys[s];
        float p = 0.f, bv = 0.f, dv = 0.f;
        if (key != 0xFFFFFFFFu) {
            unsigned i = key & IMASK;
            int b = s_lvl[i];
            unsigned rmv = rmg[i];
            unsigned inv = (~rmv) >> (b + 1);
            int d = b + 1 + (__ffs(inv) - 1);
            d = min(d, maxL);
            bv = (float)b / 10.0f;
            dv = (float)d / 10.0f;
            p = dv - bv;
        }
        outP[img * 256 + s] = p;
        outB[img * 256 + s] = bv;
        outD[img * 256 + s] = dv;
    }
}

// ================= dispatch C: wasserstein matching + final loss =============
__global__ __launch_bounds__(1024) void wdist_kernel(const float* __restrict__ outP,
                                                     const float* __restrict__ outB,
                                                     const float* __restrict__ outD,
                                                     float* __restrict__ out)
{
    int tid = threadIdx.x;
    int s = tid >> 8;
    int slot = tid & 255;
    int mi = s * 256 + slot;
    int pi = (4 + s) * 256 + slot;
    float p1 = outP[mi], b1 = outB[mi], d1 = outD[mi];
    float p2 = outP[pi], b2 = outB[pi], d2 = outD[pi];
    bool h1 = p1 > 0.f, h2 = p2 > 0.f;
    float cost = 0.f;
    if (h1 && h2)      cost = (b1 - b2) * (b1 - b2) + (d1 - d2) * (d1 - d2);
    else if (h1)       cost = p1 * p1 * 0.5f;
    else if (h2)       cost = p2 * p2 * 0.5f;

    for (int off = 32; off > 0; off >>= 1) cost += __shfl_down(cost, off);
    __shared__ float part[16];
    __shared__ float dist[4];
    int wv = tid >> 6;
    if ((tid & 63) == 0) part[wv] = cost;
    __syncthreads();
    if (tid < 4) {
        float sum = part[tid * 4] + part[tid * 4 + 1] + part[tid * 4 + 2] + part[tid * 4 + 3];
        dist[tid] = sqrtf(sum + 1e-12f);
    }
    __syncthreads();
    if (tid == 0)
        out[0] = 0.01f * (dist[0] + dist[1] + dist[2] + dist[3]) / 4.0f;
}

// ws layout (bytes):
//   lvl   u8 [8][16384]         @ 0        (131072)
//   maxL  i32[8]                @ 131072   (32)
//   argmin u32[8]               @ 131104   (32)
//   rootmask u32[8][16384]      @ 131136   (524288)
//   outP/outB/outD f32[8][256]  @ 655424   (24576)
//   flags u32[8]                @ 680000   (32)
extern "C" void kernel_launch(void* const* d_in, const int* in_sizes, int n_in,
                              void* d_out, int out_size, void* d_ws, size_t ws_size,
                              hipStream_t stream)
{
    const float* model_output = (const float*)d_in[0];
    const float* labels = (const float*)d_in[1];
    char* ws = (char*)d_ws;
    uint8_t* lvl = (uint8_t*)ws;
    int* maxL = (int*)(ws + 131072);
    unsigned* argmin = (unsigned*)(ws + 131104);
    unsigned* rootmask = (unsigned*)(ws + 131136);
    float* outP = (float*)(ws + 655424);
    float* outB = outP + NIMG * 256;
    float* outD = outB + NIMG * 256;
    unsigned* flags = (unsigned*)(ws + 680000);
    float* out = (float*)d_out;

    prep_ccl<<<96, 1024, 0, stream>>>(model_output, labels, lvl, maxL, argmin,
                                      rootmask, flags);
    death_kernel<<<NIMG, 1024, 0, stream>>>(lvl, maxL, rootmask, outP, outB, outD);
    wdist_kernel<<<1, 1024, 0, stream>>>(outP, outB, outD, out);
}